// Round 8
// baseline (36.306 us; speedup 1.0000x reference)
//
#include <hip/hip_runtime.h>
#include <math.h>

// PhaseLoss: ip + gd + ptd phase losses over [32,1,513,512] fp32 spectra.
// d'[b,f,t] = angle(ref * conj(est)); ip = |d'|;
// gd  = unwrap(d'[f-1,t] - d'[f,t])  (f-1<0 -> 0)
// ptd = unwrap(d'[f,t-1] - d'[f,t])  (t-1<0 -> 0)
// out = sum / (B*F*T)
//
// R8 structure: global_load_lds direct-to-LDS staging, wave-private double
// buffer, ZERO barriers. Each wave owns 8 f-rows (+1 halo). Per row: 8x
// global_load_lds_dwordx4 (1KB each) stage the 4 arrays' 2KB rows; explicit
// counted "s_waitcnt vmcnt(8)" + sched_barrier keeps the NEXT row's 8 loads
// in flight through every compute phase (the compiler cannot demote DMA
// loads the way it demoted register prefetch in R5/R7; VGPR=52/80 showed
// those schedules were serialized). Lane t-mapping {4l..4l+3, 256+4l..}
// makes gll layout == read layout, conflict-free b128 ds_reads.

#define NB 32
#define NF 513
#define NT 512
#define RPW 8
#define CHUNKS 65          // ceil(513/8)
#define NWAVES 2080        // 32*65
#define NBLOCKS 520        // 4 waves/block
#define NTOT 8404992LL     // 32*513*512

static __device__ __forceinline__ float fast_atan2(float y, float x) {
    const float PI_F  = 3.14159274101257324f;
    const float PI_2F = 1.57079632679489662f;
    float ax = fabsf(x), ay = fabsf(y);
    float mx = fmaxf(ax, ay), mn = fminf(ax, ay);
    float r  = mn * __builtin_amdgcn_rcpf(mx);
    r = (mx == 0.f) ? 0.f : r;
    float s = r * r;
    float p = fmaf(s, -0.01172120f, 0.05265332f);
    p = fmaf(s, p, -0.11643287f);
    p = fmaf(s, p,  0.19354346f);
    p = fmaf(s, p, -0.33262347f);
    p = fmaf(s, p,  0.99997726f);
    float a = r * p;
    a = (ay > ax) ? (PI_2F - a) : a;
    a = (x < 0.f) ? (PI_F - a) : a;
    return copysignf(a, y);
}

static __device__ __forceinline__ float pdiff(float a, float b, float c, float d) {
    // est=a+ib, ref=c+id: angle(ref*conj(est)) = atan2(d*a - c*b, c*a + d*b)
    return fast_atan2(fmaf(d, a, -(c * b)), fmaf(c, a, d * b));
}

static __device__ __forceinline__ float wrap_abs(float x) {
    const float PI_F     = 3.14159274101257324f;
    const float TWO_PI_F = 6.28318548202514648f;
    float u = fabsf(x);
    return u > PI_F ? TWO_PI_F - u : u;
}

// async global->LDS, 16B per lane: LDS dst = wave-uniform base + lane*16;
// global src = per-lane pointer.
static __device__ __forceinline__ void gll16(const float* g, float* l) {
    __builtin_amdgcn_global_load_lds(
        (const __attribute__((address_space(1))) void*)g,
        (__attribute__((address_space(3))) void*)l,
        16, 0, 0);
}

__global__ __launch_bounds__(256) void phase_loss_k(
    const float* __restrict__ er, const float* __restrict__ ei,
    const float* __restrict__ rr, const float* __restrict__ ri,
    float* __restrict__ slots)
{
    // 4 waves * 2 buffers * (4 arrays * 512 floats) = 16384 floats = 64 KB
    __shared__ float lds_arr[4 * 4096];
    const int tid  = threadIdx.x;
    const int lane = tid & 63;
    const int wave = tid >> 6;
    const int wid  = (blockIdx.x << 2) | wave;          // 0..2079
    const int b    = wid / CHUNKS;
    const int f0   = (wid - b * CHUNKS) * RPW;
    const int base = b * (NF * NT);
    const int nv   = (NF - f0 < RPW) ? (NF - f0) : RPW; // 8, or 1 on last chunk
    const int fstart = (f0 > 0) ? f0 - 1 : f0;
    const int nrows  = nv + (f0 > 0 ? 1 : 0);           // 8, 9, or 2

    float* slab = &lds_arr[wave * 4096];                // 16 KB per wave

    // stage one full row (4 arrays x 2KB) into buffer p_: 8 x 1KB DMA
#define ISSUE_ROW(p_, f_) do {                                    \
        float* _buf = slab + (p_) * 2048;                         \
        const int _ro = base + (f_) * NT + lane * 4;              \
        gll16(er + _ro,       _buf);                              \
        gll16(er + _ro + 256, _buf + 256);                        \
        gll16(ei + _ro,       _buf + 512);                        \
        gll16(ei + _ro + 256, _buf + 768);                        \
        gll16(rr + _ro,       _buf + 1024);                       \
        gll16(rr + _ro + 256, _buf + 1280);                       \
        gll16(ri + _ro,       _buf + 1536);                       \
        gll16(ri + _ro + 256, _buf + 1792);                       \
    } while (0)

    ISSUE_ROW(0, fstart);
    if (nrows > 1) ISSUE_ROW(1, fstart + 1);

    float s = 0.f;
    float dp[8];
    #pragma unroll
    for (int k = 0; k < 8; ++k) dp[k] = 0.f;

    for (int i = 0; i < nrows; ++i) {
        // row i's 8 DMAs complete; row i+1's 8 may remain in flight
        if (i + 1 < nrows) {
            asm volatile("s_waitcnt vmcnt(8)" ::: "memory");
        } else {
            asm volatile("s_waitcnt vmcnt(0)" ::: "memory");
        }
        __builtin_amdgcn_sched_barrier(0);

        const float* buf = slab + (i & 1) * 2048;
        float4 va0 = *(const float4*)(buf + lane * 4);
        float4 va1 = *(const float4*)(buf + 256  + lane * 4);
        float4 vb0 = *(const float4*)(buf + 512  + lane * 4);
        float4 vb1 = *(const float4*)(buf + 768  + lane * 4);
        float4 vc0 = *(const float4*)(buf + 1024 + lane * 4);
        float4 vc1 = *(const float4*)(buf + 1280 + lane * 4);
        float4 ve0 = *(const float4*)(buf + 1536 + lane * 4);
        float4 ve1 = *(const float4*)(buf + 1792 + lane * 4);

        // drain ds_reads, then reuse this buffer for row i+2 (stays in
        // flight through the compute below)
        asm volatile("s_waitcnt lgkmcnt(0)" ::: "memory");
        __builtin_amdgcn_sched_barrier(0);
        if (i + 2 < nrows) ISSUE_ROW(i & 1, fstart + i + 2);
        __builtin_amdgcn_sched_barrier(0);

        float d[8];
        d[0] = pdiff(va0.x, vb0.x, vc0.x, ve0.x);
        d[1] = pdiff(va0.y, vb0.y, vc0.y, ve0.y);
        d[2] = pdiff(va0.z, vb0.z, vc0.z, ve0.z);
        d[3] = pdiff(va0.w, vb0.w, vc0.w, ve0.w);
        d[4] = pdiff(va1.x, vb1.x, vc1.x, ve1.x);
        d[5] = pdiff(va1.y, vb1.y, vc1.y, ve1.y);
        d[6] = pdiff(va1.z, vb1.z, vc1.z, ve1.z);
        d[7] = pdiff(va1.w, vb1.w, vc1.w, ve1.w);

        if (i == 0 && f0 > 0) {
            // halo row: only seeds the f-1 carry
            #pragma unroll
            for (int k = 0; k < 8; ++k) dp[k] = d[k];
        } else {
            // t-neighbors: lane l group0 head t=4l -> lane l-1 d[3];
            // group1 head t=256+4l -> lane l-1 d[7]; lane0: t=0 -> 0,
            // t=256 -> element 255 = lane63's d[3].
            float t255 = __shfl(d[3], 63, 64);
            float dt0  = __shfl_up(d[3], 1, 64);
            float dt1  = __shfl_up(d[7], 1, 64);
            if (lane == 0) { dt0 = 0.f; dt1 = t255; }
            #pragma unroll
            for (int k = 0; k < 4; ++k) {
                s += fabsf(d[k]);
                s += wrap_abs(dp[k] - d[k]);
                s += wrap_abs(dt0 - d[k]);
                dt0 = d[k];
                dp[k] = d[k];
            }
            #pragma unroll
            for (int k = 4; k < 8; ++k) {
                s += fabsf(d[k]);
                s += wrap_abs(dp[k] - d[k]);
                s += wrap_abs(dt1 - d[k]);
                dt1 = d[k];
                dp[k] = d[k];
            }
        }
    }
#undef ISSUE_ROW

    // per-wave reduce, tiny cross-wave combine, one plain store per block
    #pragma unroll
    for (int off = 32; off > 0; off >>= 1)
        s += __shfl_down(s, off, 64);
    __shared__ float ws4[4];
    if (lane == 0) ws4[wave] = s;
    __syncthreads();
    if (tid == 0) slots[blockIdx.x] = ws4[0] + ws4[1] + ws4[2] + ws4[3];
}

__global__ __launch_bounds__(256) void finalize_k(const float* __restrict__ slots,
                                                  float* __restrict__ out)
{
    int tid = threadIdx.x;
    float s = 0.f;
    for (int i = tid; i < NBLOCKS; i += 256) s += slots[i];
    #pragma unroll
    for (int off = 32; off > 0; off >>= 1)
        s += __shfl_down(s, off, 64);
    __shared__ float wsum[4];
    if ((tid & 63) == 0) wsum[tid >> 6] = s;
    __syncthreads();
    if (tid == 0) {
        double tot = (double)wsum[0] + (double)wsum[1] + (double)wsum[2] + (double)wsum[3];
        out[0] = (float)(tot / (double)NTOT);
    }
}

extern "C" void kernel_launch(void* const* d_in, const int* in_sizes, int n_in,
                              void* d_out, int out_size, void* d_ws, size_t ws_size,
                              hipStream_t stream) {
    const float* er = (const float*)d_in[0];
    const float* ei = (const float*)d_in[1];
    const float* rr = (const float*)d_in[2];
    const float* ri = (const float*)d_in[3];
    float* out   = (float*)d_out;
    float* slots = (float*)d_ws;              // NBLOCKS fp32, fully rewritten each call

    phase_loss_k<<<NBLOCKS, 256, 0, stream>>>(er, ei, rr, ri, slots);
    finalize_k<<<1, 256, 0, stream>>>(slots, out);
}

// Round 9
// 33.891 us; speedup vs baseline: 1.0713x; 1.0713x over previous
//
#include <hip/hip_runtime.h>
#include <math.h>

// PhaseLoss: ip + gd + ptd phase losses over [32,1,513,512] fp32 spectra.
// d'[b,f,t] = angle(ref * conj(est)); ip = |d'|;
// gd  = unwrap(d'[f-1,t] - d'[f,t])  (f-1<0 -> 0)
// ptd = unwrap(d'[f,t-1] - d'[f,t])  (t-1<0 -> 0)
// out = sum / (B*F*T)
//
// R9 structure: byte-minimal staging. Block = 4 waves = 32 f-rows. Seed
// phase: each wave loads+computes d of its LAST row (row 7) and passes it to
// the next wave via LDS (halo[w+1]); wave 0 additionally loads the one true
// block-halo row (f0b-1). One barrier. Main loop: rows 0..6 loaded fresh
// (register f-carry dp), row 7 reuses the seed-phase d from registers.
// Halo overfetch drops from 1/8 (R3..R8: 151 MB staged) to 1/32 (138.7 MB).
// R4/R6 lessons: no fences, no hot atomics; plain slot store + tiny finalize.

#define NB 32
#define NF 513
#define NT 512
#define BPC 32             // f-rows per block
#define CHUNKS 17          // ceil(513/32) chunks per batch
#define NBLOCKS 544        // 32*17
#define NTOT 8404992LL     // 32*513*512

static __device__ __forceinline__ float fast_atan2(float y, float x) {
    const float PI_F  = 3.14159274101257324f;
    const float PI_2F = 1.57079632679489662f;
    float ax = fabsf(x), ay = fabsf(y);
    float mx = fmaxf(ax, ay), mn = fminf(ax, ay);
    float r  = mn * __builtin_amdgcn_rcpf(mx);
    r = (mx == 0.f) ? 0.f : r;
    float s = r * r;
    float p = fmaf(s, -0.01172120f, 0.05265332f);
    p = fmaf(s, p, -0.11643287f);
    p = fmaf(s, p,  0.19354346f);
    p = fmaf(s, p, -0.33262347f);
    p = fmaf(s, p,  0.99997726f);
    float a = r * p;
    a = (ay > ax) ? (PI_2F - a) : a;
    a = (x < 0.f) ? (PI_F - a) : a;
    return copysignf(a, y);
}

static __device__ __forceinline__ float pdiff(float a, float b, float c, float d) {
    // est=a+ib, ref=c+id: angle(ref*conj(est)) = atan2(d*a - c*b, c*a + d*b)
    return fast_atan2(fmaf(d, a, -(c * b)), fmaf(c, a, d * b));
}

static __device__ __forceinline__ float wrap_abs(float x) {
    const float PI_F     = 3.14159274101257324f;
    const float TWO_PI_F = 6.28318548202514648f;
    float u = fabsf(x);
    return u > PI_F ? TWO_PI_F - u : u;
}

struct Row8 { float4 a0, a1, b0, b1, c0, c1, e0, e1; };

static __device__ __forceinline__ void calc8(const Row8& r, float d[8]) {
    d[0] = pdiff(r.a0.x, r.b0.x, r.c0.x, r.e0.x);
    d[1] = pdiff(r.a0.y, r.b0.y, r.c0.y, r.e0.y);
    d[2] = pdiff(r.a0.z, r.b0.z, r.c0.z, r.e0.z);
    d[3] = pdiff(r.a0.w, r.b0.w, r.c0.w, r.e0.w);
    d[4] = pdiff(r.a1.x, r.b1.x, r.c1.x, r.e1.x);
    d[5] = pdiff(r.a1.y, r.b1.y, r.c1.y, r.e1.y);
    d[6] = pdiff(r.a1.z, r.b1.z, r.c1.z, r.e1.z);
    d[7] = pdiff(r.a1.w, r.b1.w, r.c1.w, r.e1.w);
}

// accumulate one row's three loss terms; updates dp[] (f-1 carry)
static __device__ __forceinline__ float acc_row(const float d[8], float dp[8], int lane) {
    float dt = __shfl_up(d[7], 1, 64);
    if (lane == 0) dt = 0.f;                  // t==0 neighbor
    float s = 0.f;
    #pragma unroll
    for (int k = 0; k < 8; ++k) {
        s += fabsf(d[k]);                     // ip
        s += wrap_abs(dp[k] - d[k]);          // gd
        s += wrap_abs(dt - d[k]);             // ptd
        dt = d[k];
        dp[k] = d[k];
    }
    return s;
}

__global__ __launch_bounds__(256) void phase_loss_k(
    const float* __restrict__ er, const float* __restrict__ ei,
    const float* __restrict__ rr, const float* __restrict__ ri,
    float* __restrict__ slots)
{
    __shared__ float halo[4][NT];             // d-row halo for wave w
    __shared__ float ws4[4];
    const int tid  = threadIdx.x;
    const int lane = tid & 63;
    const int wave = tid >> 6;
    const int wid  = blockIdx.x;              // 0..543
    const int b    = wid / CHUNKS;
    const int f0b  = (wid - b * CHUNKS) * BPC;
    const int f0w  = f0b + wave * 8;
    const int base = b * (NF * NT);
    const int rem  = NF - f0w;
    const int nv   = rem < 8 ? (rem < 0 ? 0 : rem) : 8;   // rows this wave owns

#define LOAD_ROW(dst, f_) do {                                   \
        const int _i = base + (f_) * NT + lane * 8;              \
        dst.a0 = *(const float4*)(er + _i);                      \
        dst.a1 = *(const float4*)(er + _i + 4);                  \
        dst.b0 = *(const float4*)(ei + _i);                      \
        dst.b1 = *(const float4*)(ei + _i + 4);                  \
        dst.c0 = *(const float4*)(rr + _i);                      \
        dst.c1 = *(const float4*)(rr + _i + 4);                  \
        dst.e0 = *(const float4*)(ri + _i);                      \
        dst.e1 = *(const float4*)(ri + _i + 4);                  \
    } while (0)

    // ---- seed phase: row-7 d per wave -> next wave's halo; wave0 loads
    //      the single true halo row of the block ----
    Row8 R7, Rh;
    const bool full  = (nv == 8);
    const bool whalo = (wave == 0) && (f0b > 0) && (nv > 0);
    if (full)  LOAD_ROW(R7, f0w + 7);
    if (whalo) LOAD_ROW(Rh, f0b - 1);

    float d7[8];
    if (full) {
        calc8(R7, d7);
        if (wave < 3) {
            *(float4*)&halo[wave + 1][lane * 8]     = make_float4(d7[0], d7[1], d7[2], d7[3]);
            *(float4*)&halo[wave + 1][lane * 8 + 4] = make_float4(d7[4], d7[5], d7[6], d7[7]);
        }
    }
    if (whalo) {
        float dh[8];
        calc8(Rh, dh);
        *(float4*)&halo[0][lane * 8]     = make_float4(dh[0], dh[1], dh[2], dh[3]);
        *(float4*)&halo[0][lane * 8 + 4] = make_float4(dh[4], dh[5], dh[6], dh[7]);
    }
    __syncthreads();

    // ---- main loop: rows 0..6 fresh, row 7 from seed-phase registers ----
    float s = 0.f;
    if (nv > 0) {
        float dp[8];
        if (f0w > 0) {
            float4 h0 = *(const float4*)&halo[wave][lane * 8];
            float4 h1 = *(const float4*)&halo[wave][lane * 8 + 4];
            dp[0] = h0.x; dp[1] = h0.y; dp[2] = h0.z; dp[3] = h0.w;
            dp[4] = h1.x; dp[5] = h1.y; dp[6] = h1.z; dp[7] = h1.w;
        } else {
            #pragma unroll
            for (int k = 0; k < 8; ++k) dp[k] = 0.f;
        }

        const int nfresh = full ? 7 : nv;     // row 7 already computed if full
        Row8 cur, nxt;
        LOAD_ROW(nxt, f0w);
        #pragma unroll
        for (int r = 0; r < 7; ++r) {
            if (r >= nfresh) break;           // wave-uniform
            cur = nxt;
            if (r + 1 < nfresh) LOAD_ROW(nxt, f0w + r + 1);
            float d[8];
            calc8(cur, d);
            s += acc_row(d, dp, lane);
        }
        if (full) s += acc_row(d7, dp, lane);
    }
#undef LOAD_ROW

    // per-wave reduce, tiny cross-wave combine, one plain store per block
    #pragma unroll
    for (int off = 32; off > 0; off >>= 1)
        s += __shfl_down(s, off, 64);
    if (lane == 0) ws4[wave] = s;
    __syncthreads();
    if (tid == 0) slots[blockIdx.x] = ws4[0] + ws4[1] + ws4[2] + ws4[3];
}

__global__ __launch_bounds__(256) void finalize_k(const float* __restrict__ slots,
                                                  float* __restrict__ out)
{
    int tid = threadIdx.x;
    float s = 0.f;
    for (int i = tid; i < NBLOCKS; i += 256) s += slots[i];
    #pragma unroll
    for (int off = 32; off > 0; off >>= 1)
        s += __shfl_down(s, off, 64);
    __shared__ float wsum[4];
    if ((tid & 63) == 0) wsum[tid >> 6] = s;
    __syncthreads();
    if (tid == 0) {
        double tot = (double)wsum[0] + (double)wsum[1] + (double)wsum[2] + (double)wsum[3];
        out[0] = (float)(tot / (double)NTOT);
    }
}

extern "C" void kernel_launch(void* const* d_in, const int* in_sizes, int n_in,
                              void* d_out, int out_size, void* d_ws, size_t ws_size,
                              hipStream_t stream) {
    const float* er = (const float*)d_in[0];
    const float* ei = (const float*)d_in[1];
    const float* rr = (const float*)d_in[2];
    const float* ri = (const float*)d_in[3];
    float* out   = (float*)d_out;
    float* slots = (float*)d_ws;              // NBLOCKS fp32, fully rewritten each call

    phase_loss_k<<<NBLOCKS, 256, 0, stream>>>(er, ei, rr, ri, slots);
    finalize_k<<<1, 256, 0, stream>>>(slots, out);
}

// Round 10
// 32.331 us; speedup vs baseline: 1.1230x; 1.0483x over previous
//
#include <hip/hip_runtime.h>
#include <math.h>

// PhaseLoss: ip + gd + ptd phase losses over [32,1,513,512] fp32 spectra.
// d'[b,f,t] = angle(ref * conj(est)); ip = |d'|;
// gd  = unwrap(d'[f-1,t] - d'[f,t])  (f-1<0 -> 0)
// ptd = unwrap(d'[f,t-1] - d'[f,t])  (t-1<0 -> 0)
// out = sum / (B*F*T)
//
// R10 structure: exact-fit persistent grid. [B,F,T] flattened to 16416
// contiguous rows of 512 (row r: b=r/513, f=r%513; address = r*512+t).
// 512 blocks = exactly 2 blocks/CU, all resident from t=0 -> no scheduling
// rounds (R9 lesson: 544 blocks = 2.125 rounds cost ~29% makespan).
// Blocks 0..479 own 32 rows, 480..511 own 33 (exact cover, +-3% balance).
// In-block halo sharing kept from R9 (seed phase + 1 barrier): staged bytes
// ~138.7 MB (3% halo overfetch). Batch boundary: rows with f==0 just reset
// the gd carry (dp=0) and skip the halo.
// R4/R6 lessons: no fences, no hot atomics; plain slot store + finalize.

#define NB 32
#define NF 513
#define NT 512
#define NROWS 16416        // 32*513
#define NBLOCKS 512
#define NTOT 8404992LL     // 32*513*512

static __device__ __forceinline__ float fast_atan2(float y, float x) {
    const float PI_F  = 3.14159274101257324f;
    const float PI_2F = 1.57079632679489662f;
    float ax = fabsf(x), ay = fabsf(y);
    float mx = fmaxf(ax, ay), mn = fminf(ax, ay);
    float r  = mn * __builtin_amdgcn_rcpf(mx);
    r = (mx == 0.f) ? 0.f : r;
    float s = r * r;
    float p = fmaf(s, -0.01172120f, 0.05265332f);
    p = fmaf(s, p, -0.11643287f);
    p = fmaf(s, p,  0.19354346f);
    p = fmaf(s, p, -0.33262347f);
    p = fmaf(s, p,  0.99997726f);
    float a = r * p;
    a = (ay > ax) ? (PI_2F - a) : a;
    a = (x < 0.f) ? (PI_F - a) : a;
    return copysignf(a, y);
}

static __device__ __forceinline__ float pdiff(float a, float b, float c, float d) {
    // est=a+ib, ref=c+id: angle(ref*conj(est)) = atan2(d*a - c*b, c*a + d*b)
    return fast_atan2(fmaf(d, a, -(c * b)), fmaf(c, a, d * b));
}

static __device__ __forceinline__ float wrap_abs(float x) {
    const float PI_F     = 3.14159274101257324f;
    const float TWO_PI_F = 6.28318548202514648f;
    float u = fabsf(x);
    return u > PI_F ? TWO_PI_F - u : u;
}

struct Row8 { float4 a0, a1, b0, b1, c0, c1, e0, e1; };

static __device__ __forceinline__ void calc8(const Row8& r, float d[8]) {
    d[0] = pdiff(r.a0.x, r.b0.x, r.c0.x, r.e0.x);
    d[1] = pdiff(r.a0.y, r.b0.y, r.c0.y, r.e0.y);
    d[2] = pdiff(r.a0.z, r.b0.z, r.c0.z, r.e0.z);
    d[3] = pdiff(r.a0.w, r.b0.w, r.c0.w, r.e0.w);
    d[4] = pdiff(r.a1.x, r.b1.x, r.c1.x, r.e1.x);
    d[5] = pdiff(r.a1.y, r.b1.y, r.c1.y, r.e1.y);
    d[6] = pdiff(r.a1.z, r.b1.z, r.c1.z, r.e1.z);
    d[7] = pdiff(r.a1.w, r.b1.w, r.c1.w, r.e1.w);
}

// accumulate one row's three loss terms; updates dp[] (f-1 carry)
static __device__ __forceinline__ float acc_row(const float d[8], float dp[8], int lane) {
    float dt = __shfl_up(d[7], 1, 64);
    if (lane == 0) dt = 0.f;                  // t==0 neighbor
    float s = 0.f;
    #pragma unroll
    for (int k = 0; k < 8; ++k) {
        s += fabsf(d[k]);                     // ip
        s += wrap_abs(dp[k] - d[k]);          // gd
        s += wrap_abs(dt - d[k]);             // ptd
        dt = d[k];
        dp[k] = d[k];
    }
    return s;
}

__global__ __launch_bounds__(256) void phase_loss_k(
    const float* __restrict__ er, const float* __restrict__ ei,
    const float* __restrict__ rr, const float* __restrict__ ri,
    float* __restrict__ slots)
{
    __shared__ float halo[4][NT];             // d of row preceding wave w's span
    __shared__ float ws4[4];
    const int tid  = threadIdx.x;
    const int lane = tid & 63;
    const int wave = tid >> 6;
    const int bid  = blockIdx.x;

    // block row-span: exact cover of 16416 rows by 512 blocks (32 or 33 rows)
    int R0, N;
    if (bid < 480) { R0 = bid * 32;                  N = 32; }
    else           { R0 = 15360 + (bid - 480) * 33;  N = 33; }
    const int r0w = R0 + wave * 8;                   // wave's first row
    const int nw  = (wave == 3) ? (N - 24) : 8;      // 8, or 9 for wave3 of 33-row blocks
    const int fw  = r0w % NF;                        // f of first row

#define LOAD_ROWR(dst, row_) do {                                \
        const int _i = (row_) * NT + lane * 8;                   \
        dst.a0 = *(const float4*)(er + _i);                      \
        dst.a1 = *(const float4*)(er + _i + 4);                  \
        dst.b0 = *(const float4*)(ei + _i);                      \
        dst.b1 = *(const float4*)(ei + _i + 4);                  \
        dst.c0 = *(const float4*)(rr + _i);                      \
        dst.c1 = *(const float4*)(rr + _i + 4);                  \
        dst.e0 = *(const float4*)(ri + _i);                      \
        dst.e1 = *(const float4*)(ri + _i + 4);                  \
    } while (0)

    // ---- seed phase: waves 0..2 compute d of their LAST row -> halo[w+1];
    //      wave 0 loads the block-halo row (R0-1) unless f==0 there ----
    Row8 R7, Rh;
    float d7[8];
    const bool haveSeed = (wave < 3);
    const bool whalo    = (wave == 0) && (fw != 0);
    if (haveSeed) LOAD_ROWR(R7, r0w + 7);
    if (whalo)    LOAD_ROWR(Rh, r0w - 1);
    if (haveSeed) {
        calc8(R7, d7);
        *(float4*)&halo[wave + 1][lane * 8]     = make_float4(d7[0], d7[1], d7[2], d7[3]);
        *(float4*)&halo[wave + 1][lane * 8 + 4] = make_float4(d7[4], d7[5], d7[6], d7[7]);
    }
    if (whalo) {
        float dh[8];
        calc8(Rh, dh);
        *(float4*)&halo[0][lane * 8]     = make_float4(dh[0], dh[1], dh[2], dh[3]);
        *(float4*)&halo[0][lane * 8 + 4] = make_float4(dh[4], dh[5], dh[6], dh[7]);
    }
    __syncthreads();

    // ---- main loop: fresh rows (7 for seed-waves, nw for wave 3);
    //      seed-waves append their register-carried row 7 ----
    float dp[8];
    if (fw != 0) {
        float4 h0 = *(const float4*)&halo[wave][lane * 8];
        float4 h1 = *(const float4*)&halo[wave][lane * 8 + 4];
        dp[0] = h0.x; dp[1] = h0.y; dp[2] = h0.z; dp[3] = h0.w;
        dp[4] = h1.x; dp[5] = h1.y; dp[6] = h1.z; dp[7] = h1.w;
    } else {
        #pragma unroll
        for (int k = 0; k < 8; ++k) dp[k] = 0.f;
    }

    float s = 0.f;
    const int nfresh = haveSeed ? 7 : nw;
    int f = fw;
    Row8 cur, nxt;
    LOAD_ROWR(nxt, r0w);
    for (int i = 0; i < nfresh; ++i) {
        cur = nxt;
        if (i + 1 < nfresh) LOAD_ROWR(nxt, r0w + i + 1);
        float d[8];
        calc8(cur, d);
        if (f == 0) {                          // batch boundary: reset gd carry
            #pragma unroll
            for (int k = 0; k < 8; ++k) dp[k] = 0.f;
        }
        s += acc_row(d, dp, lane);
        if (++f == NF) f = 0;
    }
    if (haveSeed) {                            // row r0w+7, d already in regs
        if (f == 0) {
            #pragma unroll
            for (int k = 0; k < 8; ++k) dp[k] = 0.f;
        }
        s += acc_row(d7, dp, lane);
    }
#undef LOAD_ROWR

    // per-wave reduce, tiny cross-wave combine, one plain store per block
    #pragma unroll
    for (int off = 32; off > 0; off >>= 1)
        s += __shfl_down(s, off, 64);
    if (lane == 0) ws4[wave] = s;
    __syncthreads();
    if (tid == 0) slots[bid] = ws4[0] + ws4[1] + ws4[2] + ws4[3];
}

__global__ __launch_bounds__(256) void finalize_k(const float* __restrict__ slots,
                                                  float* __restrict__ out)
{
    int tid = threadIdx.x;
    float s = 0.f;
    for (int i = tid; i < NBLOCKS; i += 256) s += slots[i];
    #pragma unroll
    for (int off = 32; off > 0; off >>= 1)
        s += __shfl_down(s, off, 64);
    __shared__ float wsum[4];
    if ((tid & 63) == 0) wsum[tid >> 6] = s;
    __syncthreads();
    if (tid == 0) {
        double tot = (double)wsum[0] + (double)wsum[1] + (double)wsum[2] + (double)wsum[3];
        out[0] = (float)(tot / (double)NTOT);
    }
}

extern "C" void kernel_launch(void* const* d_in, const int* in_sizes, int n_in,
                              void* d_out, int out_size, void* d_ws, size_t ws_size,
                              hipStream_t stream) {
    const float* er = (const float*)d_in[0];
    const float* ei = (const float*)d_in[1];
    const float* rr = (const float*)d_in[2];
    const float* ri = (const float*)d_in[3];
    float* out   = (float*)d_out;
    float* slots = (float*)d_ws;              // NBLOCKS fp32, fully rewritten each call

    phase_loss_k<<<NBLOCKS, 256, 0, stream>>>(er, ei, rr, ri, slots);
    finalize_k<<<1, 256, 0, stream>>>(slots, out);
}